// Round 2
// baseline (346.741 us; speedup 1.0000x reference)
//
#include <hip/hip_runtime.h>

// ---------------------------------------------------------------------------
// DualGCN v4: v3 + per-row ascending col sort for SpMM L2 sweep locality.
//   - sort_edges_kernel: bitonic sort (one wave per row) of each row's
//     (col,val) pairs by col. All concurrent SpMM row-groups then sweep the
//     X slab low->high together -> gather working set shrinks from 12.8 MB
//     to a moving window -> L2 hit rate up on the dominant gather stream.
//   - setup merged: rowptr(a), rowptr(b), convert_w in one launch (gridDim.y=3)
//   - SpMM / GEMM kernels unchanged from v3 (clean A/B on the sort).
// N=50000, E=800000, H=128, OUT=64.
// ---------------------------------------------------------------------------

typedef short short8 __attribute__((ext_vector_type(8)));
typedef float floatx4 __attribute__((ext_vector_type(4)));

__device__ inline unsigned short f2bf(float f) {
  unsigned u = __builtin_bit_cast(unsigned, f);
  u += 0x7fffu + ((u >> 16) & 1u);      // round-to-nearest-even
  return (unsigned short)(u >> 16);
}
__device__ inline unsigned pack2(float a, float b) {
  return (unsigned)f2bf(a) | ((unsigned)f2bf(b) << 16);
}
__device__ inline float bf_lo(unsigned w) {
  return __builtin_bit_cast(float, w << 16);
}
__device__ inline float bf_hi(unsigned w) {
  return __builtin_bit_cast(float, w & 0xffff0000u);
}

// y=0: rowptr for graph a; y=1: rowptr for graph b; y=2: convert weights.
// Wo de-interleaved into Wo0 = Wo[:, :128] and Wo1 = Wo[:, 128:].
__global__ __launch_bounds__(256) void setup_kernel(
    const int* __restrict__ rowA, const int* __restrict__ rowB,
    int E, int n, int* __restrict__ rpa, int* __restrict__ rpb,
    const float* __restrict__ Wa0, const float* __restrict__ Wa1,
    const float* __restrict__ Wb0, const float* __restrict__ Wb1,
    const float* __restrict__ Wm,  const float* __restrict__ Wo,
    unsigned short* __restrict__ Wout)
{
  if (blockIdx.y == 2) {
    for (int i = blockIdx.x * 256 + threadIdx.x; i < 131072; i += gridDim.x * 256) {
      float v;
      if      (i < 16384)  v = Wa0[i];
      else if (i < 32768)  v = Wa1[i - 16384];
      else if (i < 49152)  v = Wb0[i - 32768];
      else if (i < 65536)  v = Wb1[i - 49152];
      else if (i < 114688) v = Wm[i - 65536];
      else {
        int o = i - 114688;           // [0, 16384)
        int half = o >> 13;           // 0 -> Wo0, 1 -> Wo1
        int idx = o & 8191;
        int r = idx >> 7, c = idx & 127;
        v = Wo[r * 256 + half * 128 + c];
      }
      Wout[i] = f2bf(v);
    }
    return;
  }
  int i = blockIdx.x * blockDim.x + threadIdx.x;
  if (i > n) return;
  const int* row = blockIdx.y ? rowB : rowA;
  int* rp = blockIdx.y ? rpb : rpa;
  int lo = 0, hi = E;
  while (lo < hi) {
    int mid = (lo + hi) >> 1;
    if (row[mid] < i) lo = mid + 1; else hi = mid;
  }
  rp[i] = lo;
}

// One wave per row: bitonic-sort the row's (col,val) pairs ascending by col.
// deg <= 64 expected (Binomial mean 16); deg > 64 falls back to plain copy.
__global__ __launch_bounds__(256) void sort_edges_kernel(
    const int* __restrict__ rpa, const int* __restrict__ rpb,
    const int* __restrict__ colA, const float* __restrict__ valA,
    const int* __restrict__ colB, const float* __restrict__ valB,
    int* __restrict__ colA2, float* __restrict__ valA2,
    int* __restrict__ colB2, float* __restrict__ valB2, int n)
{
  int r = blockIdx.x * 4 + (threadIdx.x >> 6);
  if (r >= n) return;
  const int*   rp  = blockIdx.y ? rpb  : rpa;
  const int*   col = blockIdx.y ? colB : colA;
  const float* val = blockIdx.y ? valB : valA;
  int*   col2 = blockIdx.y ? colB2 : colA2;
  float* val2 = blockIdx.y ? valB2 : valA2;

  const int lane = threadIdx.x & 63;
  int e0 = rp[r], e1 = rp[r + 1];
  int deg = e1 - e0;
  if (deg > 64) {           // rare fallback: copy unsorted (still correct)
    for (int e = e0 + lane; e < e1; e += 64) { col2[e] = col[e]; val2[e] = val[e]; }
    return;
  }
  int   c = (lane < deg) ? col[e0 + lane] : 0x7fffffff;
  float v = (lane < deg) ? val[e0 + lane] : 0.f;

#pragma unroll
  for (int k = 2; k <= 64; k <<= 1) {
#pragma unroll
    for (int j = k >> 1; j > 0; j >>= 1) {
      int   pc = __shfl_xor(c, j, 64);
      float pv = __shfl_xor(v, j, 64);
      bool up      = (lane & k) == 0;      // ascending sub-block (k=64: all up)
      bool lower   = (lane & j) == 0;
      bool takeMin = (lower == up);
      bool sw = takeMin ? (pc < c) : (pc > c);
      if (sw) { c = pc; v = pv; }
    }
  }
  if (lane < deg) { col2[e0 + lane] = c; val2[e0 + lane] = v; }
}

// ---------------------------------------------------------------------------
// SpMM: Y[r,:] = sum_e val[e] * X[col[e],:]
// WIDTH bf16 features/row; WIDTH/8 lanes per row, 16 B gather per lane.
// Edge loop x4-unrolled with next-iteration col/val prefetch.
// ---------------------------------------------------------------------------
template <int WIDTH, bool OUTF32>
__global__ __launch_bounds__(256) void spmm_kernel(
    const int* __restrict__ rowptr, const int* __restrict__ col,
    const float* __restrict__ val, const unsigned short* __restrict__ X,
    void* __restrict__ Yv, int n)
{
  constexpr int LPR = WIDTH / 8;        // lanes per row
  constexpr int GPB = 256 / LPR;        // row-groups per block
  int g = blockIdx.x * GPB + (threadIdx.x / LPR);
  int lane = threadIdx.x & (LPR - 1);
  if (g >= n) return;
  int e0 = rowptr[g], e1 = rowptr[g + 1];

  float a0 = 0.f, a1 = 0.f, a2 = 0.f, a3 = 0.f;
  float a4 = 0.f, a5 = 0.f, a6 = 0.f, a7 = 0.f;
  const size_t loff = (size_t)lane * 8;

  auto accum = [&](int c, float v) {
    uint4 w = *(const uint4*)(X + (size_t)c * WIDTH + loff);
    a0 = fmaf(v, bf_lo(w.x), a0);
    a1 = fmaf(v, bf_hi(w.x), a1);
    a2 = fmaf(v, bf_lo(w.y), a2);
    a3 = fmaf(v, bf_hi(w.y), a3);
    a4 = fmaf(v, bf_lo(w.z), a4);
    a5 = fmaf(v, bf_hi(w.z), a5);
    a6 = fmaf(v, bf_lo(w.w), a6);
    a7 = fmaf(v, bf_hi(w.w), a7);
  };

  int e = e0;
  int epro = (e0 + 3) & ~3;             // align to 4 for vector col/val loads
  if (epro > e1) epro = e1;
  for (; e < epro; ++e) accum(col[e], val[e]);

  int4 c4 = make_int4(0, 0, 0, 0);
  float4 v4 = make_float4(0.f, 0.f, 0.f, 0.f);
  if (e + 4 <= e1) { c4 = *(const int4*)(col + e); v4 = *(const float4*)(val + e); }
  for (; e + 4 <= e1; ) {
    uint4 w0 = *(const uint4*)(X + (size_t)c4.x * WIDTH + loff);
    uint4 w1 = *(const uint4*)(X + (size_t)c4.y * WIDTH + loff);
    uint4 w2 = *(const uint4*)(X + (size_t)c4.z * WIDTH + loff);
    uint4 w3 = *(const uint4*)(X + (size_t)c4.w * WIDTH + loff);
    int en = e + 4;
    int4 c4n = make_int4(0, 0, 0, 0);
    float4 v4n = make_float4(0.f, 0.f, 0.f, 0.f);
    if (en + 4 <= e1) { c4n = *(const int4*)(col + en); v4n = *(const float4*)(val + en); }
    a0 = fmaf(v4.x, bf_lo(w0.x), a0); a1 = fmaf(v4.x, bf_hi(w0.x), a1);
    a2 = fmaf(v4.x, bf_lo(w0.y), a2); a3 = fmaf(v4.x, bf_hi(w0.y), a3);
    a4 = fmaf(v4.x, bf_lo(w0.z), a4); a5 = fmaf(v4.x, bf_hi(w0.z), a5);
    a6 = fmaf(v4.x, bf_lo(w0.w), a6); a7 = fmaf(v4.x, bf_hi(w0.w), a7);
    a0 = fmaf(v4.y, bf_lo(w1.x), a0); a1 = fmaf(v4.y, bf_hi(w1.x), a1);
    a2 = fmaf(v4.y, bf_lo(w1.y), a2); a3 = fmaf(v4.y, bf_hi(w1.y), a3);
    a4 = fmaf(v4.y, bf_lo(w1.z), a4); a5 = fmaf(v4.y, bf_hi(w1.z), a5);
    a6 = fmaf(v4.y, bf_lo(w1.w), a6); a7 = fmaf(v4.y, bf_hi(w1.w), a7);
    a0 = fmaf(v4.z, bf_lo(w2.x), a0); a1 = fmaf(v4.z, bf_hi(w2.x), a1);
    a2 = fmaf(v4.z, bf_lo(w2.y), a2); a3 = fmaf(v4.z, bf_hi(w2.y), a3);
    a4 = fmaf(v4.z, bf_lo(w2.z), a4); a5 = fmaf(v4.z, bf_hi(w2.z), a5);
    a6 = fmaf(v4.z, bf_lo(w2.w), a6); a7 = fmaf(v4.z, bf_hi(w2.w), a7);
    a0 = fmaf(v4.w, bf_lo(w3.x), a0); a1 = fmaf(v4.w, bf_hi(w3.x), a1);
    a2 = fmaf(v4.w, bf_lo(w3.y), a2); a3 = fmaf(v4.w, bf_hi(w3.y), a3);
    a4 = fmaf(v4.w, bf_lo(w3.z), a4); a5 = fmaf(v4.w, bf_hi(w3.z), a5);
    a6 = fmaf(v4.w, bf_lo(w3.w), a6); a7 = fmaf(v4.w, bf_hi(w3.w), a7);
    c4 = c4n; v4 = v4n; e = en;
  }
  for (; e < e1; ++e) accum(col[e], val[e]);

  if (OUTF32) {
    float* Y = (float*)Yv;
    float4 o0; o0.x = a0; o0.y = a1; o0.z = a2; o0.w = a3;
    float4 o1; o1.x = a4; o1.y = a5; o1.z = a6; o1.w = a7;
    *(float4*)(Y + (size_t)g * WIDTH + lane * 8) = o0;
    *(float4*)(Y + (size_t)g * WIDTH + lane * 8 + 4) = o1;
  } else {
    uint4 o;
    o.x = pack2(a0, a1); o.y = pack2(a2, a3);
    o.z = pack2(a4, a5); o.w = pack2(a6, a7);
    *(uint4*)((unsigned short*)Yv + (size_t)g * WIDTH + loff) = o;
  }
}

// ---------------------------------------------------------------------------
// Shared GEMM building blocks (unchanged from v3).
// Block: 256 thr = 4 waves in 2x2 (wm,wn); tile 128 rows x HOUT cols.
// X tile staged in LDS (padded); W fragments read straight from global.
// ---------------------------------------------------------------------------
#define LDXP 136   // padded LDS row stride (bf16 units)

__device__ inline void stage_bf16(const unsigned short* __restrict__ Xp,
                                  unsigned short* Xs, int row0, int n,
                                  int rloc, int c8)
{
#pragma unroll
  for (int p = 0; p < 8; ++p) {
    int r = p * 16 + rloc;
    int gr = row0 + r;
    uint4 v = make_uint4(0u, 0u, 0u, 0u);
    if (gr < n) v = *(const uint4*)(Xp + (size_t)gr * 128 + c8);
    *(uint4*)(Xs + r * LDXP + c8) = v;
  }
}

template <int NT>
__device__ inline void mfma_phase(const unsigned short* __restrict__ W, int Kstride,
                                  int kc, const unsigned short* Xs,
                                  int wm, int wn, int l15, int quad,
                                  floatx4 (&acc)[4][NT])
{
#pragma unroll
  for (int k0 = 0; k0 < 128; k0 += 32) {
    const int ko = k0 + quad * 8;
    short8 aW[NT], bX[4];
#pragma unroll
    for (int j = 0; j < NT; ++j)
      aW[j] = *(const short8*)(W + (size_t)(wn * (16 * NT) + j * 16 + l15) * Kstride + kc + ko);
#pragma unroll
    for (int i = 0; i < 4; ++i)
      bX[i] = *(const short8*)(Xs + (wm * 64 + i * 16 + l15) * LDXP + ko);
#pragma unroll
    for (int i = 0; i < 4; ++i)
#pragma unroll
      for (int j = 0; j < NT; ++j)
        acc[i][j] = __builtin_amdgcn_mfma_f32_16x16x32_bf16(aW[j], bX[i], acc[i][j], 0, 0, 0);
  }
}

// Y = (relu?)(X @ W.T + b [+ add]), X = up to 3 bf16 slabs (free concat).
template <int K, int HOUT, bool RELU, bool OUTBF, bool ADDEND>
__global__ __launch_bounds__(256, 2) void gemm_std_kernel(
    const unsigned short* __restrict__ X0, const unsigned short* __restrict__ X1,
    const unsigned short* __restrict__ X2, const unsigned short* __restrict__ W,
    const float* __restrict__ b, const float* __restrict__ add,
    void* __restrict__ Yv, int n)
{
  constexpr int NT = HOUT / 32;
  __shared__ unsigned short Xs[128 * LDXP];
  const int tid = threadIdx.x;
  const int lane = tid & 63;
  const int wave = tid >> 6;
  const int wm = wave >> 1;
  const int wn = wave & 1;
  const int l15 = lane & 15;
  const int quad = lane >> 4;
  const int row0 = blockIdx.x * 128;
  const int c8 = (tid & 15) * 8;
  const int rloc = tid >> 4;

  floatx4 acc[4][NT];
#pragma unroll
  for (int i = 0; i < 4; ++i)
#pragma unroll
    for (int j = 0; j < NT; ++j) acc[i][j] = (floatx4){0.f, 0.f, 0.f, 0.f};

  for (int kc = 0; kc < K; kc += 128) {
    const unsigned short* Xp = (kc == 0) ? X0 : (kc == 128) ? X1 : X2;
    if (kc) __syncthreads();
    stage_bf16(Xp, Xs, row0, n, rloc, c8);
    __syncthreads();
    mfma_phase<NT>(W, K, kc, Xs, wm, wn, l15, quad, acc);
  }

#pragma unroll
  for (int i = 0; i < 4; ++i) {
    int r = row0 + wm * 64 + i * 16 + l15;
    if (r >= n) continue;
#pragma unroll
    for (int j = 0; j < NT; ++j) {
      int c0 = wn * (16 * NT) + j * 16 + quad * 4;
      float4 bb = *(const float4*)(b + c0);
      float v0 = acc[i][j][0] + bb.x;
      float v1 = acc[i][j][1] + bb.y;
      float v2 = acc[i][j][2] + bb.z;
      float v3 = acc[i][j][3] + bb.w;
      if (ADDEND) {
        float4 ad = *(const float4*)(add + (size_t)r * HOUT + c0);
        v0 += ad.x; v1 += ad.y; v2 += ad.z; v3 += ad.w;
      }
      if (RELU) {
        v0 = fmaxf(v0, 0.f); v1 = fmaxf(v1, 0.f);
        v2 = fmaxf(v2, 0.f); v3 = fmaxf(v3, 0.f);
      }
      if (OUTBF) {
        uint2 o; o.x = pack2(v0, v1); o.y = pack2(v2, v3);
        *(uint2*)((unsigned short*)Yv + (size_t)r * HOUT + c0) = o;
      } else {
        float4 o; o.x = v0; o.y = v1; o.z = v2; o.w = v3;
        *(float4*)((float*)Yv + (size_t)r * HOUT + c0) = o;
      }
    }
  }
}

// A = relu(x@W1.T+b1), C = relu(x@W2.T+b2) from fp32 x, shared X staging.
__global__ __launch_bounds__(256, 2) void gemm_dual_f32_kernel(
    const float* __restrict__ X, const unsigned short* __restrict__ W1,
    const unsigned short* __restrict__ W2, const float* __restrict__ b1,
    const float* __restrict__ b2, unsigned short* __restrict__ Y1,
    unsigned short* __restrict__ Y2, int n)
{
  constexpr int NT = 4;  // HOUT = 128
  __shared__ unsigned short Xs[128 * LDXP];
  const int tid = threadIdx.x;
  const int lane = tid & 63;
  const int wave = tid >> 6;
  const int wm = wave >> 1;
  const int wn = wave & 1;
  const int l15 = lane & 15;
  const int quad = lane >> 4;
  const int row0 = blockIdx.x * 128;
  const int c8 = (tid & 15) * 8;
  const int rloc = tid >> 4;

#pragma unroll
  for (int p = 0; p < 8; ++p) {
    int r = p * 16 + rloc;
    int gr = row0 + r;
    uint4 o = make_uint4(0u, 0u, 0u, 0u);
    if (gr < n) {
      float4 f0 = *(const float4*)(X + (size_t)gr * 128 + c8);
      float4 f1 = *(const float4*)(X + (size_t)gr * 128 + c8 + 4);
      o.x = pack2(f0.x, f0.y); o.y = pack2(f0.z, f0.w);
      o.z = pack2(f1.x, f1.y); o.w = pack2(f1.z, f1.w);
    }
    *(uint4*)(Xs + r * LDXP + c8) = o;
  }
  __syncthreads();

  for (int s = 0; s < 2; ++s) {
    const unsigned short* W = s ? W2 : W1;
    const float* b = s ? b2 : b1;
    unsigned short* Y = s ? Y2 : Y1;
    floatx4 acc[4][NT];
#pragma unroll
    for (int i = 0; i < 4; ++i)
#pragma unroll
      for (int j = 0; j < NT; ++j) acc[i][j] = (floatx4){0.f, 0.f, 0.f, 0.f};
    mfma_phase<NT>(W, 128, 0, Xs, wm, wn, l15, quad, acc);
#pragma unroll
    for (int i = 0; i < 4; ++i) {
      int r = row0 + wm * 64 + i * 16 + l15;
      if (r >= n) continue;
#pragma unroll
      for (int j = 0; j < NT; ++j) {
        int c0 = wn * 64 + j * 16 + quad * 4;
        float4 bb = *(const float4*)(b + c0);
        float v0 = fmaxf(acc[i][j][0] + bb.x, 0.f);
        float v1 = fmaxf(acc[i][j][1] + bb.y, 0.f);
        float v2 = fmaxf(acc[i][j][2] + bb.z, 0.f);
        float v3 = fmaxf(acc[i][j][3] + bb.w, 0.f);
        uint2 o; o.x = pack2(v0, v1); o.y = pack2(v2, v3);
        *(uint2*)(Y + (size_t)r * 128 + c0) = o;
      }
    }
  }
}

// Q = (relu(B@Wa1.T + ba1)) @ Wo0.T  — two chained MFMA stages through LDS;
// the intermediate A2 never touches global memory.
__global__ __launch_bounds__(256, 2) void gemm_chain_kernel(
    const unsigned short* __restrict__ X, const unsigned short* __restrict__ W1,
    const float* __restrict__ b1, const unsigned short* __restrict__ W2,
    unsigned short* __restrict__ Q, int n)
{
  __shared__ unsigned short Xs[128 * LDXP];
  const int tid = threadIdx.x;
  const int lane = tid & 63;
  const int wave = tid >> 6;
  const int wm = wave >> 1;
  const int wn = wave & 1;
  const int l15 = lane & 15;
  const int quad = lane >> 4;
  const int row0 = blockIdx.x * 128;
  const int c8 = (tid & 15) * 8;
  const int rloc = tid >> 4;

  stage_bf16(X, Xs, row0, n, rloc, c8);
  __syncthreads();

  // stage 1: A2 = relu(B @ Wa1.T + ba1), HOUT=128
  floatx4 acc1[4][4];
#pragma unroll
  for (int i = 0; i < 4; ++i)
#pragma unroll
    for (int j = 0; j < 4; ++j) acc1[i][j] = (floatx4){0.f, 0.f, 0.f, 0.f};
  mfma_phase<4>(W1, 128, 0, Xs, wm, wn, l15, quad, acc1);
  __syncthreads();   // all stage-1 reads of Xs done before overwrite

  // bias+relu, pack bf16, write A2 tile back into Xs
#pragma unroll
  for (int i = 0; i < 4; ++i) {
    int r2 = wm * 64 + i * 16 + l15;
#pragma unroll
    for (int j = 0; j < 4; ++j) {
      int c2 = wn * 64 + j * 16 + quad * 4;
      float4 bb = *(const float4*)(b1 + c2);
      float v0 = fmaxf(acc1[i][j][0] + bb.x, 0.f);
      float v1 = fmaxf(acc1[i][j][1] + bb.y, 0.f);
      float v2 = fmaxf(acc1[i][j][2] + bb.z, 0.f);
      float v3 = fmaxf(acc1[i][j][3] + bb.w, 0.f);
      uint2 o; o.x = pack2(v0, v1); o.y = pack2(v2, v3);
      *(uint2*)(Xs + r2 * LDXP + c2) = o;
    }
  }
  __syncthreads();

  // stage 2: Q = A2 @ Wo0.T, HOUT=64 (pure, no bias)
  floatx4 acc2[4][2];
#pragma unroll
  for (int i = 0; i < 4; ++i)
#pragma unroll
    for (int j = 0; j < 2; ++j) acc2[i][j] = (floatx4){0.f, 0.f, 0.f, 0.f};
  mfma_phase<2>(W2, 128, 0, Xs, wm, wn, l15, quad, acc2);

#pragma unroll
  for (int i = 0; i < 4; ++i) {
    int r = row0 + wm * 64 + i * 16 + l15;
    if (r >= n) continue;
#pragma unroll
    for (int j = 0; j < 2; ++j) {
      int c0 = wn * 32 + j * 16 + quad * 4;
      uint2 o;
      o.x = pack2(acc2[i][j][0], acc2[i][j][1]);
      o.y = pack2(acc2[i][j][2], acc2[i][j][3]);
      *(uint2*)(Q + (size_t)r * 64 + c0) = o;
    }
  }
}

extern "C" void kernel_launch(void* const* d_in, const int* in_sizes, int n_in,
                              void* d_out, int out_size, void* d_ws, size_t ws_size,
                              hipStream_t stream)
{
  const float* x     = (const float*)d_in[0];
  const int*   row_a = (const int*)d_in[1];
  const int*   col_a = (const int*)d_in[2];
  const float* val_a = (const float*)d_in[3];
  const int*   row_b = (const int*)d_in[4];
  const int*   col_b = (const int*)d_in[5];
  const float* val_b = (const float*)d_in[6];
  const float* Wa0 = (const float*)d_in[7];  const float* ba0 = (const float*)d_in[8];
  const float* Wa1 = (const float*)d_in[9];  const float* ba1 = (const float*)d_in[10];
  const float* Wb0 = (const float*)d_in[11]; const float* bb0 = (const float*)d_in[12];
  const float* Wb1 = (const float*)d_in[13]; const float* bb1 = (const float*)d_in[14];
  const float* Wm  = (const float*)d_in[15]; const float* bm  = (const float*)d_in[16];
  const float* Wo  = (const float*)d_in[17]; const float* bo  = (const float*)d_in[18];
  float* out = (float*)d_out;

  const int n = in_sizes[0] / 128;   // 50000
  const int E = in_sizes[1];         // 800000

  char* ws = (char*)d_ws;
  size_t off = 0;
  auto alloc = [&](size_t bytes) {
    void* p = ws + off;
    off = (off + bytes + 255) & ~(size_t)255;
    return p;
  };
  int* rpa = (int*)alloc((size_t)(n + 1) * sizeof(int));
  int* rpb = (int*)alloc((size_t)(n + 1) * sizeof(int));
  unsigned short* Wcat = (unsigned short*)alloc(131072 * sizeof(unsigned short));
  int*   col2a = (int*)alloc((size_t)E * sizeof(int));
  float* val2a = (float*)alloc((size_t)E * sizeof(float));
  int*   col2b = (int*)alloc((size_t)E * sizeof(int));
  float* val2b = (float*)alloc((size_t)E * sizeof(float));
  const size_t slab = (size_t)n * 128 * sizeof(unsigned short);
  unsigned short* A  = (unsigned short*)alloc(slab);   // branch-a hidden
  unsigned short* C  = (unsigned short*)alloc(slab);   // g0
  unsigned short* B  = (unsigned short*)alloc(slab);   // spmm scratch (reused)
  unsigned short* D  = (unsigned short*)alloc(slab);   // g1
  unsigned short* A3 = (unsigned short*)alloc(slab);   // x_b
  unsigned short* Q  = (unsigned short*)alloc((size_t)n * 64 * sizeof(unsigned short));
  float* Pout = (float*)alloc((size_t)n * 64 * sizeof(float)); // x_a @ Wo0^T

  const unsigned short* Wa0b = Wcat;
  const unsigned short* Wa1b = Wcat + 16384;
  const unsigned short* Wb0b = Wcat + 32768;
  const unsigned short* Wb1b = Wcat + 49152;
  const unsigned short* Wmb  = Wcat + 65536;
  const unsigned short* Wo0b = Wcat + 114688;
  const unsigned short* Wo1b = Wcat + 122880;

  dim3 blk(256);
  dim3 g_setup((n + 1 + 255) / 256, 3);
  dim3 g_sort((n + 3) / 4, 2);
  dim3 g_lin((n + 127) / 128);
  dim3 g_sp((n + 15) / 16);
  dim3 g_sp64((n + 31) / 32);

  setup_kernel<<<g_setup, blk, 0, stream>>>(row_a, row_b, E, n, rpa, rpb,
                                            Wa0, Wa1, Wb0, Wb1, Wm, Wo, Wcat);
  sort_edges_kernel<<<g_sort, blk, 0, stream>>>(rpa, rpb, col_a, val_a,
                                                col_b, val_b, col2a, val2a,
                                                col2b, val2b, n);

  // A = relu(x Wa0^T + ba0), C = relu(x Wb0^T + bb0)   (shared x staging)
  gemm_dual_f32_kernel<<<g_lin, blk, 0, stream>>>(x, Wa0b, Wb0b, ba0, bb0, A, C, n);

  // branch a (commuted tail): Pout = spmm_a(relu(spmm_a(A) Wa1^T + ba1) Wo0^T)
  spmm_kernel<128, false><<<g_sp, blk, 0, stream>>>(rpa, col2a, val2a, A, B, n);
  gemm_chain_kernel<<<g_lin, blk, 0, stream>>>(B, Wa1b, ba1, Wo0b, Q, n);
  spmm_kernel<64, true><<<g_sp64, blk, 0, stream>>>(rpa, col2a, val2a, Q, Pout, n);

  // branch b
  spmm_kernel<128, false><<<g_sp, blk, 0, stream>>>(rpb, col2b, val2b, C, B, n);
  gemm_std_kernel<128, 128, true, true, false><<<g_lin, blk, 0, stream>>>(
      B, nullptr, nullptr, Wb1b, bb1, nullptr, D, n);                      // g1
  spmm_kernel<128, false><<<g_sp, blk, 0, stream>>>(rpb, col2b, val2b, D, B, n); // g2
  gemm_std_kernel<384, 128, true, true, false><<<g_lin, blk, 0, stream>>>(
      C, D, B, Wmb, bm, nullptr, A3, n);                                   // x_b

  // out = x_b Wo1^T + bo + Pout   (fp32 out)
  gemm_std_kernel<128, 64, false, false, true><<<g_lin, blk, 0, stream>>>(
      A3, nullptr, nullptr, Wo1b, bo, Pout, out, n);
}

// Round 3
// 301.121 us; speedup vs baseline: 1.1515x; 1.1515x over previous
//
#include <hip/hip_runtime.h>

// ---------------------------------------------------------------------------
// DualGCN v5: v3 structure (sort reverted) + depth-2 pipelined SpMM gathers
//             + merged independent SpMM launches.
//   - SpMM inner loop: col/val prefetched TWO batches ahead so batch t+1's
//     X-gather addresses are ready without draining batch t's gathers
//     (vmcnt is in-order: address-dep on a NEWER load drains older gathers).
//     8 gathers in flight per row-group vs 4 before.
//   - spmm_dual128: graph-a and graph-b first SpMMs in one launch (y=0/1).
//   - spmm_mixed:   graph-b 128-wide + graph-a 64-wide tail SpMM in one.
//   - GEMMs unchanged from v3 (verified).
// N=50000, E=800000, H=128, OUT=64.
// ---------------------------------------------------------------------------

typedef short short8 __attribute__((ext_vector_type(8)));
typedef float floatx4 __attribute__((ext_vector_type(4)));

__device__ inline unsigned short f2bf(float f) {
  unsigned u = __builtin_bit_cast(unsigned, f);
  u += 0x7fffu + ((u >> 16) & 1u);      // round-to-nearest-even
  return (unsigned short)(u >> 16);
}
__device__ inline unsigned pack2(float a, float b) {
  return (unsigned)f2bf(a) | ((unsigned)f2bf(b) << 16);
}
__device__ inline float bf_lo(unsigned w) {
  return __builtin_bit_cast(float, w << 16);
}
__device__ inline float bf_hi(unsigned w) {
  return __builtin_bit_cast(float, w & 0xffff0000u);
}

// y=0: rowptr for graph a; y=1: rowptr for graph b; y=2: convert weights.
// Wo de-interleaved into Wo0 = Wo[:, :128] and Wo1 = Wo[:, 128:].
__global__ __launch_bounds__(256) void setup_kernel(
    const int* __restrict__ rowA, const int* __restrict__ rowB,
    int E, int n, int* __restrict__ rpa, int* __restrict__ rpb,
    const float* __restrict__ Wa0, const float* __restrict__ Wa1,
    const float* __restrict__ Wb0, const float* __restrict__ Wb1,
    const float* __restrict__ Wm,  const float* __restrict__ Wo,
    unsigned short* __restrict__ Wout)
{
  if (blockIdx.y == 2) {
    for (int i = blockIdx.x * 256 + threadIdx.x; i < 131072; i += gridDim.x * 256) {
      float v;
      if      (i < 16384)  v = Wa0[i];
      else if (i < 32768)  v = Wa1[i - 16384];
      else if (i < 49152)  v = Wb0[i - 32768];
      else if (i < 65536)  v = Wb1[i - 49152];
      else if (i < 114688) v = Wm[i - 65536];
      else {
        int o = i - 114688;           // [0, 16384)
        int half = o >> 13;           // 0 -> Wo0, 1 -> Wo1
        int idx = o & 8191;
        int r = idx >> 7, c = idx & 127;
        v = Wo[r * 256 + half * 128 + c];
      }
      Wout[i] = f2bf(v);
    }
    return;
  }
  int i = blockIdx.x * blockDim.x + threadIdx.x;
  if (i > n) return;
  const int* row = blockIdx.y ? rowB : rowA;
  int* rp = blockIdx.y ? rpb : rpa;
  int lo = 0, hi = E;
  while (lo < hi) {
    int mid = (lo + hi) >> 1;
    if (row[mid] < i) lo = mid + 1; else hi = mid;
  }
  rp[i] = lo;
}

// ---------------------------------------------------------------------------
// SpMM row body: Y[g,:] = sum_e val[e] * X[col[e],:]
// WIDTH bf16 features; WIDTH/8 lanes per row, 16 B gather per lane.
// Depth-2 software pipeline: col/val prefetched 2 batches ahead, X gathers
// issued 1 batch ahead -> 8 outstanding 16 B gathers per row-group.
// ---------------------------------------------------------------------------
template <int WIDTH, bool OUTF32>
__device__ __forceinline__ void spmm_rows(
    const int* __restrict__ rowptr, const int* __restrict__ col,
    const float* __restrict__ val, const unsigned short* __restrict__ X,
    void* __restrict__ Yv, int n, int bx)
{
  constexpr int LPR = WIDTH / 8;        // lanes per row
  constexpr int GPB = 256 / LPR;        // row-groups per block
  int g = bx * GPB + ((int)threadIdx.x / LPR);
  int lane = threadIdx.x & (LPR - 1);
  if (g >= n) return;
  int e0 = rowptr[g], e1 = rowptr[g + 1];

  float a0 = 0.f, a1 = 0.f, a2 = 0.f, a3 = 0.f;
  float a4 = 0.f, a5 = 0.f, a6 = 0.f, a7 = 0.f;
  const size_t loff = (size_t)lane * 8;

  auto gat = [&](int c) -> uint4 {
    return *(const uint4*)(X + (size_t)c * WIDTH + loff);
  };
  auto fma1 = [&](float v, uint4 w) {
    a0 = fmaf(v, bf_lo(w.x), a0); a1 = fmaf(v, bf_hi(w.x), a1);
    a2 = fmaf(v, bf_lo(w.y), a2); a3 = fmaf(v, bf_hi(w.y), a3);
    a4 = fmaf(v, bf_lo(w.z), a4); a5 = fmaf(v, bf_hi(w.z), a5);
    a6 = fmaf(v, bf_lo(w.w), a6); a7 = fmaf(v, bf_hi(w.w), a7);
  };
  auto accum = [&](int c, float v) { fma1(v, gat(c)); };

  int e = e0;
  int epro = (e0 + 3) & ~3;             // align to 4 for vector col/val loads
  if (epro > e1) epro = e1;
  for (; e < epro; ++e) accum(col[e], val[e]);

  int nb = (e1 - e) >> 2;               // full 4-edge batches
  if (nb > 0) {
    int4   cA = *(const int4*)(col + e);
    float4 vA = *(const float4*)(val + e);
    int4   cB = cA; float4 vB = vA;
    if (nb > 1) { cB = *(const int4*)(col + e + 4); vB = *(const float4*)(val + e + 4); }
    uint4 w0 = gat(cA.x), w1 = gat(cA.y), w2 = gat(cA.z), w3 = gat(cA.w);
    for (int t = 0; t < nb - 1; ++t) {
      int4 cC = cB; float4 vC = vB;
      if (t + 2 < nb) {
        cC = *(const int4*)(col + e + 4 * (t + 2));
        vC = *(const float4*)(val + e + 4 * (t + 2));
      }
      // gathers for batch t+1 (addresses loaded 2 iterations ago -> no drain)
      uint4 u0 = gat(cB.x), u1 = gat(cB.y), u2 = gat(cB.z), u3 = gat(cB.w);
      // FMA batch t
      fma1(vA.x, w0); fma1(vA.y, w1); fma1(vA.z, w2); fma1(vA.w, w3);
      vA = vB; vB = vC; cB = cC;
      w0 = u0; w1 = u1; w2 = u2; w3 = u3;
    }
    fma1(vA.x, w0); fma1(vA.y, w1); fma1(vA.z, w2); fma1(vA.w, w3);
    e += nb * 4;
  }
  for (; e < e1; ++e) accum(col[e], val[e]);

  if (OUTF32) {
    float* Y = (float*)Yv;
    float4 o0; o0.x = a0; o0.y = a1; o0.z = a2; o0.w = a3;
    float4 o1; o1.x = a4; o1.y = a5; o1.z = a6; o1.w = a7;
    *(float4*)(Y + (size_t)g * WIDTH + lane * 8) = o0;
    *(float4*)(Y + (size_t)g * WIDTH + lane * 8 + 4) = o1;
  } else {
    uint4 o;
    o.x = pack2(a0, a1); o.y = pack2(a2, a3);
    o.z = pack2(a4, a5); o.w = pack2(a6, a7);
    *(uint4*)((unsigned short*)Yv + (size_t)g * WIDTH + loff) = o;
  }
}

// y=0: graph a, Xa->Ya; y=1: graph b, Xb->Yb (both 128-wide, bf16 out)
__global__ __launch_bounds__(256) void spmm_dual128_kernel(
    const int* __restrict__ rpa, const int* __restrict__ cola,
    const float* __restrict__ vala, const unsigned short* __restrict__ Xa,
    unsigned short* __restrict__ Ya,
    const int* __restrict__ rpb, const int* __restrict__ colb,
    const float* __restrict__ valb, const unsigned short* __restrict__ Xb,
    unsigned short* __restrict__ Yb, int n)
{
  if (blockIdx.y == 0)
    spmm_rows<128, false>(rpa, cola, vala, Xa, Ya, n, blockIdx.x);
  else
    spmm_rows<128, false>(rpb, colb, valb, Xb, Yb, n, blockIdx.x);
}

// y=0: graph b 128-wide D->Yb (bf16); y=1: graph a 64-wide Q->Pout (f32)
__global__ __launch_bounds__(256) void spmm_mixed_kernel(
    const int* __restrict__ rpb, const int* __restrict__ colb,
    const float* __restrict__ valb, const unsigned short* __restrict__ D,
    unsigned short* __restrict__ Yb,
    const int* __restrict__ rpa, const int* __restrict__ cola,
    const float* __restrict__ vala, const unsigned short* __restrict__ Q,
    float* __restrict__ Pout, int n)
{
  if (blockIdx.y == 0)
    spmm_rows<128, false>(rpb, colb, valb, D, Yb, n, blockIdx.x);
  else
    spmm_rows<64, true>(rpa, cola, vala, Q, Pout, n, blockIdx.x);
}

// ---------------------------------------------------------------------------
// GEMM building blocks (unchanged from v3).
// Block: 256 thr = 4 waves in 2x2 (wm,wn); tile 128 rows x HOUT cols.
// X tile staged in LDS (padded); W fragments read straight from global.
// ---------------------------------------------------------------------------
#define LDXP 136   // padded LDS row stride (bf16 units)

__device__ inline void stage_bf16(const unsigned short* __restrict__ Xp,
                                  unsigned short* Xs, int row0, int n,
                                  int rloc, int c8)
{
#pragma unroll
  for (int p = 0; p < 8; ++p) {
    int r = p * 16 + rloc;
    int gr = row0 + r;
    uint4 v = make_uint4(0u, 0u, 0u, 0u);
    if (gr < n) v = *(const uint4*)(Xp + (size_t)gr * 128 + c8);
    *(uint4*)(Xs + r * LDXP + c8) = v;
  }
}

template <int NT>
__device__ inline void mfma_phase(const unsigned short* __restrict__ W, int Kstride,
                                  int kc, const unsigned short* Xs,
                                  int wm, int wn, int l15, int quad,
                                  floatx4 (&acc)[4][NT])
{
#pragma unroll
  for (int k0 = 0; k0 < 128; k0 += 32) {
    const int ko = k0 + quad * 8;
    short8 aW[NT], bX[4];
#pragma unroll
    for (int j = 0; j < NT; ++j)
      aW[j] = *(const short8*)(W + (size_t)(wn * (16 * NT) + j * 16 + l15) * Kstride + kc + ko);
#pragma unroll
    for (int i = 0; i < 4; ++i)
      bX[i] = *(const short8*)(Xs + (wm * 64 + i * 16 + l15) * LDXP + ko);
#pragma unroll
    for (int i = 0; i < 4; ++i)
#pragma unroll
      for (int j = 0; j < NT; ++j)
        acc[i][j] = __builtin_amdgcn_mfma_f32_16x16x32_bf16(aW[j], bX[i], acc[i][j], 0, 0, 0);
  }
}

// Y = (relu?)(X @ W.T + b [+ add]), X = up to 3 bf16 slabs (free concat).
template <int K, int HOUT, bool RELU, bool OUTBF, bool ADDEND>
__global__ __launch_bounds__(256, 2) void gemm_std_kernel(
    const unsigned short* __restrict__ X0, const unsigned short* __restrict__ X1,
    const unsigned short* __restrict__ X2, const unsigned short* __restrict__ W,
    const float* __restrict__ b, const float* __restrict__ add,
    void* __restrict__ Yv, int n)
{
  constexpr int NT = HOUT / 32;
  __shared__ unsigned short Xs[128 * LDXP];
  const int tid = threadIdx.x;
  const int lane = tid & 63;
  const int wave = tid >> 6;
  const int wm = wave >> 1;
  const int wn = wave & 1;
  const int l15 = lane & 15;
  const int quad = lane >> 4;
  const int row0 = blockIdx.x * 128;
  const int c8 = (tid & 15) * 8;
  const int rloc = tid >> 4;

  floatx4 acc[4][NT];
#pragma unroll
  for (int i = 0; i < 4; ++i)
#pragma unroll
    for (int j = 0; j < NT; ++j) acc[i][j] = (floatx4){0.f, 0.f, 0.f, 0.f};

  for (int kc = 0; kc < K; kc += 128) {
    const unsigned short* Xp = (kc == 0) ? X0 : (kc == 128) ? X1 : X2;
    if (kc) __syncthreads();
    stage_bf16(Xp, Xs, row0, n, rloc, c8);
    __syncthreads();
    mfma_phase<NT>(W, K, kc, Xs, wm, wn, l15, quad, acc);
  }

#pragma unroll
  for (int i = 0; i < 4; ++i) {
    int r = row0 + wm * 64 + i * 16 + l15;
    if (r >= n) continue;
#pragma unroll
    for (int j = 0; j < NT; ++j) {
      int c0 = wn * (16 * NT) + j * 16 + quad * 4;
      float4 bb = *(const float4*)(b + c0);
      float v0 = acc[i][j][0] + bb.x;
      float v1 = acc[i][j][1] + bb.y;
      float v2 = acc[i][j][2] + bb.z;
      float v3 = acc[i][j][3] + bb.w;
      if (ADDEND) {
        float4 ad = *(const float4*)(add + (size_t)r * HOUT + c0);
        v0 += ad.x; v1 += ad.y; v2 += ad.z; v3 += ad.w;
      }
      if (RELU) {
        v0 = fmaxf(v0, 0.f); v1 = fmaxf(v1, 0.f);
        v2 = fmaxf(v2, 0.f); v3 = fmaxf(v3, 0.f);
      }
      if (OUTBF) {
        uint2 o; o.x = pack2(v0, v1); o.y = pack2(v2, v3);
        *(uint2*)((unsigned short*)Yv + (size_t)r * HOUT + c0) = o;
      } else {
        float4 o; o.x = v0; o.y = v1; o.z = v2; o.w = v3;
        *(float4*)((float*)Yv + (size_t)r * HOUT + c0) = o;
      }
    }
  }
}

// A = relu(x@W1.T+b1), C = relu(x@W2.T+b2) from fp32 x, shared X staging.
__global__ __launch_bounds__(256, 2) void gemm_dual_f32_kernel(
    const float* __restrict__ X, const unsigned short* __restrict__ W1,
    const unsigned short* __restrict__ W2, const float* __restrict__ b1,
    const float* __restrict__ b2, unsigned short* __restrict__ Y1,
    unsigned short* __restrict__ Y2, int n)
{
  constexpr int NT = 4;  // HOUT = 128
  __shared__ unsigned short Xs[128 * LDXP];
  const int tid = threadIdx.x;
  const int lane = tid & 63;
  const int wave = tid >> 6;
  const int wm = wave >> 1;
  const int wn = wave & 1;
  const int l15 = lane & 15;
  const int quad = lane >> 4;
  const int row0 = blockIdx.x * 128;
  const int c8 = (tid & 15) * 8;
  const int rloc = tid >> 4;

#pragma unroll
  for (int p = 0; p < 8; ++p) {
    int r = p * 16 + rloc;
    int gr = row0 + r;
    uint4 o = make_uint4(0u, 0u, 0u, 0u);
    if (gr < n) {
      float4 f0 = *(const float4*)(X + (size_t)gr * 128 + c8);
      float4 f1 = *(const float4*)(X + (size_t)gr * 128 + c8 + 4);
      o.x = pack2(f0.x, f0.y); o.y = pack2(f0.z, f0.w);
      o.z = pack2(f1.x, f1.y); o.w = pack2(f1.z, f1.w);
    }
    *(uint4*)(Xs + r * LDXP + c8) = o;
  }
  __syncthreads();

  for (int s = 0; s < 2; ++s) {
    const unsigned short* W = s ? W2 : W1;
    const float* b = s ? b2 : b1;
    unsigned short* Y = s ? Y2 : Y1;
    floatx4 acc[4][NT];
#pragma unroll
    for (int i = 0; i < 4; ++i)
#pragma unroll
      for (int j = 0; j < NT; ++j) acc[i][j] = (floatx4){0.f, 0.f, 0.f, 0.f};
    mfma_phase<NT>(W, 128, 0, Xs, wm, wn, l15, quad, acc);
#pragma unroll
    for (int i = 0; i < 4; ++i) {
      int r = row0 + wm * 64 + i * 16 + l15;
      if (r >= n) continue;
#pragma unroll
      for (int j = 0; j < NT; ++j) {
        int c0 = wn * 64 + j * 16 + quad * 4;
        float4 bb = *(const float4*)(b + c0);
        float v0 = fmaxf(acc[i][j][0] + bb.x, 0.f);
        float v1 = fmaxf(acc[i][j][1] + bb.y, 0.f);
        float v2 = fmaxf(acc[i][j][2] + bb.z, 0.f);
        float v3 = fmaxf(acc[i][j][3] + bb.w, 0.f);
        uint2 o; o.x = pack2(v0, v1); o.y = pack2(v2, v3);
        *(uint2*)(Y + (size_t)r * 128 + c0) = o;
      }
    }
  }
}

// Q = (relu(B@Wa1.T + ba1)) @ Wo0.T  — two chained MFMA stages through LDS;
// the intermediate A2 never touches global memory.
__global__ __launch_bounds__(256, 2) void gemm_chain_kernel(
    const unsigned short* __restrict__ X, const unsigned short* __restrict__ W1,
    const float* __restrict__ b1, const unsigned short* __restrict__ W2,
    unsigned short* __restrict__ Q, int n)
{
  __shared__ unsigned short Xs[128 * LDXP];
  const int tid = threadIdx.x;
  const int lane = tid & 63;
  const int wave = tid >> 6;
  const int wm = wave >> 1;
  const int wn = wave & 1;
  const int l15 = lane & 15;
  const int quad = lane >> 4;
  const int row0 = blockIdx.x * 128;
  const int c8 = (tid & 15) * 8;
  const int rloc = tid >> 4;

  stage_bf16(X, Xs, row0, n, rloc, c8);
  __syncthreads();

  // stage 1: A2 = relu(B @ Wa1.T + ba1), HOUT=128
  floatx4 acc1[4][4];
#pragma unroll
  for (int i = 0; i < 4; ++i)
#pragma unroll
    for (int j = 0; j < 4; ++j) acc1[i][j] = (floatx4){0.f, 0.f, 0.f, 0.f};
  mfma_phase<4>(W1, 128, 0, Xs, wm, wn, l15, quad, acc1);
  __syncthreads();   // all stage-1 reads of Xs done before overwrite

  // bias+relu, pack bf16, write A2 tile back into Xs
#pragma unroll
  for (int i = 0; i < 4; ++i) {
    int r2 = wm * 64 + i * 16 + l15;
#pragma unroll
    for (int j = 0; j < 4; ++j) {
      int c2 = wn * 64 + j * 16 + quad * 4;
      float4 bb = *(const float4*)(b1 + c2);
      float v0 = fmaxf(acc1[i][j][0] + bb.x, 0.f);
      float v1 = fmaxf(acc1[i][j][1] + bb.y, 0.f);
      float v2 = fmaxf(acc1[i][j][2] + bb.z, 0.f);
      float v3 = fmaxf(acc1[i][j][3] + bb.w, 0.f);
      uint2 o; o.x = pack2(v0, v1); o.y = pack2(v2, v3);
      *(uint2*)(Xs + r2 * LDXP + c2) = o;
    }
  }
  __syncthreads();

  // stage 2: Q = A2 @ Wo0.T, HOUT=64 (pure, no bias)
  floatx4 acc2[4][2];
#pragma unroll
  for (int i = 0; i < 4; ++i)
#pragma unroll
    for (int j = 0; j < 2; ++j) acc2[i][j] = (floatx4){0.f, 0.f, 0.f, 0.f};
  mfma_phase<2>(W2, 128, 0, Xs, wm, wn, l15, quad, acc2);

#pragma unroll
  for (int i = 0; i < 4; ++i) {
    int r = row0 + wm * 64 + i * 16 + l15;
    if (r >= n) continue;
#pragma unroll
    for (int j = 0; j < 2; ++j) {
      int c0 = wn * 32 + j * 16 + quad * 4;
      uint2 o;
      o.x = pack2(acc2[i][j][0], acc2[i][j][1]);
      o.y = pack2(acc2[i][j][2], acc2[i][j][3]);
      *(uint2*)(Q + (size_t)r * 64 + c0) = o;
    }
  }
}

extern "C" void kernel_launch(void* const* d_in, const int* in_sizes, int n_in,
                              void* d_out, int out_size, void* d_ws, size_t ws_size,
                              hipStream_t stream)
{
  const float* x     = (const float*)d_in[0];
  const int*   row_a = (const int*)d_in[1];
  const int*   col_a = (const int*)d_in[2];
  const float* val_a = (const float*)d_in[3];
  const int*   row_b = (const int*)d_in[4];
  const int*   col_b = (const int*)d_in[5];
  const float* val_b = (const float*)d_in[6];
  const float* Wa0 = (const float*)d_in[7];  const float* ba0 = (const float*)d_in[8];
  const float* Wa1 = (const float*)d_in[9];  const float* ba1 = (const float*)d_in[10];
  const float* Wb0 = (const float*)d_in[11]; const float* bb0 = (const float*)d_in[12];
  const float* Wb1 = (const float*)d_in[13]; const float* bb1 = (const float*)d_in[14];
  const float* Wm  = (const float*)d_in[15]; const float* bm  = (const float*)d_in[16];
  const float* Wo  = (const float*)d_in[17]; const float* bo  = (const float*)d_in[18];
  float* out = (float*)d_out;

  const int n = in_sizes[0] / 128;   // 50000
  const int E = in_sizes[1];         // 800000

  char* ws = (char*)d_ws;
  size_t off = 0;
  auto alloc = [&](size_t bytes) {
    void* p = ws + off;
    off = (off + bytes + 255) & ~(size_t)255;
    return p;
  };
  int* rpa = (int*)alloc((size_t)(n + 1) * sizeof(int));
  int* rpb = (int*)alloc((size_t)(n + 1) * sizeof(int));
  unsigned short* Wcat = (unsigned short*)alloc(131072 * sizeof(unsigned short));
  const size_t slab = (size_t)n * 128 * sizeof(unsigned short);
  unsigned short* A  = (unsigned short*)alloc(slab);   // branch-a hidden
  unsigned short* C  = (unsigned short*)alloc(slab);   // g0
  unsigned short* B  = (unsigned short*)alloc(slab);   // graph-a sp1 out / g2
  unsigned short* B2 = (unsigned short*)alloc(slab);   // graph-b sp1 out
  unsigned short* D  = (unsigned short*)alloc(slab);   // g1
  unsigned short* A3 = (unsigned short*)alloc(slab);   // x_b
  unsigned short* Q  = (unsigned short*)alloc((size_t)n * 64 * sizeof(unsigned short));
  float* Pout = (float*)alloc((size_t)n * 64 * sizeof(float)); // x_a @ Wo0^T

  const unsigned short* Wa0b = Wcat;
  const unsigned short* Wa1b = Wcat + 16384;
  const unsigned short* Wb0b = Wcat + 32768;
  const unsigned short* Wb1b = Wcat + 49152;
  const unsigned short* Wmb  = Wcat + 65536;
  const unsigned short* Wo0b = Wcat + 114688;
  const unsigned short* Wo1b = Wcat + 122880;

  dim3 blk(256);
  dim3 g_setup((n + 1 + 255) / 256, 3);
  dim3 g_lin((n + 127) / 128);
  dim3 g_sp2((n + 15) / 16, 2);

  setup_kernel<<<g_setup, blk, 0, stream>>>(row_a, row_b, E, n, rpa, rpb,
                                            Wa0, Wa1, Wb0, Wb1, Wm, Wo, Wcat);

  // A = relu(x Wa0^T + ba0), C = relu(x Wb0^T + bb0)   (shared x staging)
  gemm_dual_f32_kernel<<<g_lin, blk, 0, stream>>>(x, Wa0b, Wb0b, ba0, bb0, A, C, n);

  // independent first SpMMs of both branches in one launch
  spmm_dual128_kernel<<<g_sp2, blk, 0, stream>>>(
      rpa, col_a, val_a, A, B,      // graph a: A -> B
      rpb, col_b, val_b, C, B2, n); // graph b: C -> B2

  // branch a commuted tail stage 1: Q = relu(B Wa1^T + ba1) Wo0^T
  gemm_chain_kernel<<<g_lin, blk, 0, stream>>>(B, Wa1b, ba1, Wo0b, Q, n);
  // branch b: g1 = relu(B2 Wb1^T + bb1)
  gemm_std_kernel<128, 128, true, true, false><<<g_lin, blk, 0, stream>>>(
      B2, nullptr, nullptr, Wb1b, bb1, nullptr, D, n);

  // independent tail SpMMs in one launch: g2 = spmm_b(D), Pout = spmm_a(Q)
  spmm_mixed_kernel<<<g_sp2, blk, 0, stream>>>(
      rpb, col_b, val_b, D, B,      // graph b: D -> B (g2)
      rpa, col_a, val_a, Q, Pout, n);

  // x_b = relu([g0,g1,g2] Wm^T + bm)
  gemm_std_kernel<384, 128, true, true, false><<<g_lin, blk, 0, stream>>>(
      C, D, B, Wmb, bm, nullptr, A3, n);

  // out = x_b Wo1^T + bo + Pout   (fp32 out)
  gemm_std_kernel<128, 64, false, false, true><<<g_lin, blk, 0, stream>>>(
      A3, nullptr, nullptr, Wo1b, bo, Pout, out, n);
}